// Round 8
// baseline (1536.931 us; speedup 1.0000x reference)
//
#include <hip/hip_runtime.h>
#include <math.h>

#define V 23
#define HH 256
#define BB 512
#define LL 1024
#define NOUT 46   // 2V
#define NW 8      // waves per block
#define RPW 32    // rows per wave (NW*RPW == HH)

// Multiplicative inverses mod 23, packed 5 bits/entry into two u64 scalars.
constexpr unsigned long long packInv(int lo) {
    const int inv[23] = {0,1,12,8,6,14,4,10,3,18,7,21,2,16,5,20,13,19,9,17,15,11,22};
    unsigned long long t = 0;
    for (int i = 0; i < 12; ++i) {
        int idx = lo + i;
        if (idx < 23) t |= (unsigned long long)inv[idx] << (5 * i);
    }
    return t;
}
constexpr unsigned long long INV_T0 = packInv(0);
constexpr unsigned long long INV_T1 = packInv(12);

// VALU max-reduce step via DPP (no DS pipe)
#define DPPMAX(v, ctrl, rmask)                                                  \
    do {                                                                        \
        unsigned _t = (unsigned)__builtin_amdgcn_update_dpp(                    \
            (int)(v), (int)(v), (ctrl), (rmask), 0xF, false);                   \
        (v) = ((v) > _t) ? (v) : _t;                                            \
    } while (0)

// 8 waves/block, lane-pair-replicated h ownership (wave-private v buffer,
// ONE barrier/step). W2 lives in LDS (row-major [256][46]): the register
// allocator refuses VGPR residency for a W2 array in every configuration
// (R4/R6: 56 VGPRs, R7: 32 VGPRs => scratch spills + VMEM machinery in the
// loop). Scalar ds_read_b32 at immediate offsets is conflict-free (per
// instruction the 46 active lanes read 46 consecutive words => <=2-way).
__global__ __launch_bounds__(512, 4)
void daf_kernel(const int* __restrict__ xtok,
                const float* __restrict__ W1,
                const float* __restrict__ b1,
                const float* __restrict__ W2,
                const float* __restrict__ b2,
                float* __restrict__ out)
{
    __shared__ float sW1[V * HH];          // 23552 B
    __shared__ float sW2[HH * NOUT];       // 47104 B, row-major [256][46]
    __shared__ float sVw[NW][RPW];         // relu(h), wave-private chunks
    __shared__ float sP[2][NW][64];        // partials [parity][wave][lane]
    __shared__ unsigned char sTokB[LL];    // tokens 0..22 as bytes
    __shared__ unsigned char sKB[LL];      // emitted symbols as bytes
    // total 78848 B -> 2 blocks/CU

    const int tid  = threadIdx.x;
    const int w    = tid >> 6;
    const int l    = tid & 63;
    const int b    = blockIdx.x;
    const int hrow = RPW * w + (l & (RPW - 1));   // row this lane maintains

    for (int i = tid; i < V * HH; i += 512) sW1[i] = W1[i];
    for (int i = tid; i < HH * NOUT; i += 512) sW2[i] = W2[i];
    for (int i = tid; i < LL; i += 512) sTokB[i] = (unsigned char)xtok[(size_t)b * LL + i];

    // Lane roles: lanes 0..22 own net[:V] (loc), lanes 32..54 own net[V:] (scale).
    const bool activeA = (l < V);
    const bool activeB = (l >= 32 && l < 32 + V);
    const bool active  = activeA || activeB;
    const int  col     = activeA ? l : (activeB ? (l - 32 + V) : 0);

    // h in double: 1024 sequential adds stay within 1 ulp of exact c@W1+b1.
    double h_pre = (double)b1[hrow];

    const float bias = active ? b2[col] : 0.f;

    // per-lane W2 base: column col, rows RPW*w .. RPW*w+31 (imm offsets ii*184B)
    const float* __restrict__ w2r = &sW2[(RPW * w) * NOUT + col];

    __syncthreads();

    for (int t = 0; t < LL; ++t) {
        const int tok = (int)sTokB[t];   // issued early; hidden under matvec

        // publish v = relu(h) into this wave's PRIVATE chunk (lanes l and
        // l+32 write the same value to the same address: benign)
        float v = fmaxf((float)h_pre, 0.f);
        sVw[w][l & (RPW - 1)] = v;

        // matvec partial over the wave's own 32 rows: v via broadcast b128,
        // W2 via conflict-free scalar LDS reads at immediate offsets
        const float4* pv = (const float4*)sVw[w];
        float a0 = 0.f, a1 = 0.f, a2 = 0.f, a3 = 0.f;
        #pragma unroll
        for (int q = 0; q < 8; ++q) {
            float4 vv = pv[q];
            a0 = fmaf(vv.x, w2r[(4 * q + 0) * NOUT], a0);
            a1 = fmaf(vv.y, w2r[(4 * q + 1) * NOUT], a1);
            a2 = fmaf(vv.z, w2r[(4 * q + 2) * NOUT], a2);
            a3 = fmaf(vv.w, w2r[(4 * q + 3) * NOUT], a3);
        }
        const int p = t & 1;
        sP[p][w][l] = (a0 + a1) + (a2 + a3);   // stride-4B, conflict-free
        __syncthreads();   // the ONLY barrier per step

        // gather 8 wave-partials (consecutive-word reads, imm offsets),
        // fixed-order pairwise tree -> deterministic net
        float s0 = sP[p][0][l], s1 = sP[p][1][l], s2 = sP[p][2][l], s3 = sP[p][3][l];
        float s4 = sP[p][4][l], s5 = sP[p][5][l], s6 = sP[p][6][l], s7 = sP[p][7][l];
        float net = bias + (((s0 + s1) + (s2 + s3)) + ((s4 + s5) + (s6 + s7)));

        int ib = __float_as_int(net);
        unsigned monoraw = (ib < 0) ? ~(unsigned)ib : ((unsigned)ib ^ 0x80000000u);
        const unsigned orig = active ? monoraw : 0u;  // lane's OWN key

        // dual 32-lane-half max-reduce on the VALU via DPP (replicated in
        // every wave -> every wave derives k locally, no second barrier)
        unsigned red = orig;
        DPPMAX(red, 0xB1,  0xF);  // quad_perm xor1
        DPPMAX(red, 0x4E,  0xF);  // quad_perm xor2
        DPPMAX(red, 0x141, 0xF);  // row_half_mirror
        DPPMAX(red, 0x140, 0xF);  // row_mirror
        DPPMAX(red, 0x142, 0xA);  // row_bcast15 into rows 1,3
        const unsigned sA = (unsigned)__builtin_amdgcn_readlane((int)red, 16);
        const unsigned sB = (unsigned)__builtin_amdgcn_readlane((int)red, 48);

        // winner = lowest lane whose ORIGINAL key equals its half's max
        // (lowest lane == lowest index == np first-max tie-break)
        const unsigned cmpv = (l < 32) ? sA : sB;
        const unsigned long long bal = __ballot(orig == cmpv);
        const int loc = __builtin_ctzll(bal & 0xFFFFFFFFull);
        const int sc  = __builtin_ctzll(bal >> 32);

        // inverse mod 23 from packed scalar table (no LDS on the chain)
        const unsigned long long tt = (sc < 12) ? INV_T0 : INV_T1;
        const int sh  = 5 * (sc - ((sc >= 12) ? 12 : 0));
        const int inv = (int)((tt >> sh) & 31);

        int m = tok - loc;
        m += (m >> 31) & V;            // (tok - loc) mod 23
        const int k = (m * inv) % V;   // compiler magic-mul for %23

        h_pre += (double)sW1[k * HH + hrow];   // consecutive words, dup x2: free
        if (tid == 0) sKB[t] = (unsigned char)k;
    }

    __syncthreads();
    float* outb = out + (size_t)b * LL * V;
    for (int t = tid; t < LL; t += 512)
        outb[t * V + (int)sKB[t]] = 1.0f;
}

extern "C" void kernel_launch(void* const* d_in, const int* in_sizes, int n_in,
                              void* d_out, int out_size, void* d_ws, size_t ws_size,
                              hipStream_t stream) {
    const int*   xtok = (const int*)d_in[0];
    const float* W1   = (const float*)d_in[1];
    const float* b1   = (const float*)d_in[2];
    const float* W2   = (const float*)d_in[3];
    const float* b2   = (const float*)d_in[4];
    float* out = (float*)d_out;

    // d_out poisoned 0xAA pre-launch: zero it, kernel scatters the 1.0s
    hipMemsetAsync(out, 0, (size_t)out_size * sizeof(float), stream);
    daf_kernel<<<BB, 512, 0, stream>>>(xtok, W1, b1, W2, b2, out);
}

// Round 9
// 792.510 us; speedup vs baseline: 1.9393x; 1.9393x over previous
//
#include <hip/hip_runtime.h>
#include <math.h>

#define V 23
#define HH 256
#define BB 512
#define LL 1024
#define NOUT 46  // 2V

// Multiplicative inverses mod 23, packed 5 bits/entry into two u64 scalars.
constexpr unsigned long long packInv(int lo) {
    const int inv[23] = {0,1,12,8,6,14,4,10,3,18,7,21,2,16,5,20,13,19,9,17,15,11,22};
    unsigned long long t = 0;
    for (int i = 0; i < 12; ++i) {
        int idx = lo + i;
        if (idx < 23) t |= (unsigned long long)inv[idx] << (5 * i);
    }
    return t;
}
constexpr unsigned long long INV_T0 = packInv(0);
constexpr unsigned long long INV_T1 = packInv(12);

// VALU max-reduce step via DPP (no DS pipe)
#define DPPMAX(v, ctrl, rmask)                                                  \
    do {                                                                        \
        unsigned _t = (unsigned)__builtin_amdgcn_update_dpp(                    \
            (int)(v), (int)(v), (ctrl), (rmask), 0xF, false);                   \
        (v) = ((v) > _t) ? (v) : _t;                                            \
    } while (0)

// 4 waves / 256 threads. W2 registers are sourced from LDS ACROSS A BARRIER:
// global loads get rematerialized into the loop by the backend (R4/R6,
// VGPR=56), asm pins force scratch (R7, VGPR=32), per-step LDS reads saturate
// the DS pipe (R8, 1537us). ds_read results cannot be sunk past barriers +
// in-loop LDS writes, so these 16 float4s must stay VGPR-resident.
__global__ __launch_bounds__(256, 2)
void daf_kernel(const int* __restrict__ xtok,
                const float* __restrict__ W1,
                const float* __restrict__ b1,
                const float* __restrict__ W2,
                const float* __restrict__ b2,
                float* __restrict__ out)
{
    __shared__ float sW1[V * HH];          // 23552 B, h-update rows
    __shared__ float sW2T[NOUT * HH];      // 47104 B, TRANSPOSED: [col][row]
    __shared__ float sV[HH];               // relu(h); wave-private 64-chunks
    __shared__ float sP[2][4][64];         // partials [parity][wave][lane]
    __shared__ unsigned char sTokB[LL];    // tokens as bytes
    __shared__ unsigned char sKB[LL];      // emitted symbols as bytes
    // total 76032 B -> 2 blocks/CU

    const int tid = threadIdx.x;
    const int w   = tid >> 6;
    const int l   = tid & 63;
    const int b   = blockIdx.x;

    for (int i = tid; i < V * HH; i += 256) sW1[i] = W1[i];
    // transpose W2 into LDS: sW2T[col*256 + row] = W2[row*46 + col]
    for (int i = tid; i < NOUT * HH; i += 256) {
        const int col = i >> 8, row = i & 255;
        sW2T[i] = W2[row * NOUT + col];
    }
    for (int i = tid; i < LL; i += 256) sTokB[i] = (unsigned char)xtok[(size_t)b * LL + i];

    // Lane roles: lanes 0..22 own net[:V] (loc), lanes 32..54 own net[V:] (scale).
    const bool activeA = (l < V);
    const bool activeB = (l >= 32 && l < 32 + V);
    const bool active  = activeA || activeB;
    const int  col     = activeA ? l : (activeB ? (l - 32 + V) : 0);

    // h in double: 1024 sequential adds stay within 1 ulp of exact c@W1+b1.
    double h_pre = (double)b1[tid];
    const float bias = active ? b2[col] : 0.f;

    __syncthreads();   // sW2T ready

    // Pre-loop: pull this lane's W2 column-chunk (rows 64w..64w+63, col) from
    // LDS into 16 float4 registers. One-time bank conflicts are irrelevant.
    float4 wr[16];
    {
        const float4* src = (const float4*)&sW2T[col * HH + 64 * w];
        #pragma unroll
        for (int q = 0; q < 16; ++q) wr[q] = src[q];
    }
    __syncthreads();   // remat fence: ds_reads can't sink past this

    for (int t = 0; t < LL; ++t) {
        const int tok = (int)sTokB[t];   // issued early; hidden under matvec

        // publish v = relu(h); wave w's chunk is written by its own lanes
        float v = fmaxf((float)h_pre, 0.f);
        sV[tid] = v;

        // matvec partial: rows 64w..64w+63, v via b128 broadcast reads
        const float4* pv = (const float4*)(sV + 64 * w);
        float a0 = 0.f, a1 = 0.f, a2 = 0.f, a3 = 0.f;
        #pragma unroll
        for (int q = 0; q < 16; ++q) {
            float4 vv = pv[q];
            a0 = fmaf(vv.x, wr[q].x, a0);
            a1 = fmaf(vv.y, wr[q].y, a1);
            a2 = fmaf(vv.z, wr[q].z, a2);
            a3 = fmaf(vv.w, wr[q].w, a3);
        }
        const int p = t & 1;
        sP[p][w][l] = (a0 + a1) + (a2 + a3);   // stride-4B, conflict-free
        __syncthreads();   // the ONLY barrier per step

        // gather 4 wave-partials with conflict-free scalar reads (the R6
        // float4 gather was 16B-stride => 4-way conflicts, 12.6M counter)
        float s0 = sP[p][0][l], s1 = sP[p][1][l];
        float s2 = sP[p][2][l], s3 = sP[p][3][l];
        float net = bias + ((s0 + s1) + (s2 + s3));   // same tree as R6

        int ib = __float_as_int(net);
        unsigned monoraw = (ib < 0) ? ~(unsigned)ib : ((unsigned)ib ^ 0x80000000u);
        const unsigned orig = active ? monoraw : 0u;  // lane's OWN key

        // dual 32-lane-half max-reduce on the VALU via DPP
        unsigned red = orig;
        DPPMAX(red, 0xB1,  0xF);  // quad_perm xor1
        DPPMAX(red, 0x4E,  0xF);  // quad_perm xor2
        DPPMAX(red, 0x141, 0xF);  // row_half_mirror
        DPPMAX(red, 0x140, 0xF);  // row_mirror
        DPPMAX(red, 0x142, 0xA);  // row_bcast15 into rows 1,3
        const unsigned sA = (unsigned)__builtin_amdgcn_readlane((int)red, 16);
        const unsigned sB = (unsigned)__builtin_amdgcn_readlane((int)red, 48);

        // winner = lowest lane whose ORIGINAL key equals its half's max
        // (lowest lane == lowest index == np first-max tie-break)
        const unsigned cmpv = (l < 32) ? sA : sB;
        const unsigned long long bal = __ballot(orig == cmpv);
        const int loc = __builtin_ctzll(bal & 0xFFFFFFFFull);
        const int sc  = __builtin_ctzll(bal >> 32);

        // inverse mod 23 from packed scalar table
        const unsigned long long tt = (sc < 12) ? INV_T0 : INV_T1;
        const int sh  = 5 * (sc - ((sc >= 12) ? 12 : 0));
        const int inv = (int)((tt >> sh) & 31);

        int m = tok - loc;
        m += (m >> 31) & V;            // (tok - loc) mod 23
        const int k = (m * inv) % V;   // compiler magic-mul for %23

        h_pre += (double)sW1[k * HH + tid];   // consecutive words, conflict-free
        if (tid == 0) sKB[t] = (unsigned char)k;
    }

    __syncthreads();
    float* outb = out + (size_t)b * LL * V;
    for (int t = tid; t < LL; t += 256)
        outb[t * V + (int)sKB[t]] = 1.0f;
}

extern "C" void kernel_launch(void* const* d_in, const int* in_sizes, int n_in,
                              void* d_out, int out_size, void* d_ws, size_t ws_size,
                              hipStream_t stream) {
    const int*   xtok = (const int*)d_in[0];
    const float* W1   = (const float*)d_in[1];
    const float* b1   = (const float*)d_in[2];
    const float* W2   = (const float*)d_in[3];
    const float* b2   = (const float*)d_in[4];
    float* out = (float*)d_out;

    // d_out poisoned 0xAA pre-launch: zero it, kernel scatters the 1.0s
    hipMemsetAsync(out, 0, (size_t)out_size * sizeof(float), stream);
    daf_kernel<<<BB, 256, 0, stream>>>(xtok, W1, b1, W2, b2, out);
}